// Round 6
// baseline (955.130 us; speedup 1.0000x reference)
//
#include <hip/hip_runtime.h>

typedef int vint4 __attribute__((ext_vector_type(4)));

#define NUM_XCD 8

// ---------------- common geometry ----------------
struct V3 { float x, y, z; };

__device__ __forceinline__ void compute_tet(
    V3 v0, V3 v1, V3 v2, V3 v3, float d, float& area, float& alpha)
{
    float e1x = v1.x - v0.x, e1y = v1.y - v0.y, e1z = v1.z - v0.z;
    float e2x = v2.x - v0.x, e2y = v2.y - v0.y, e2z = v2.z - v0.z;
    float e3x = v3.x - v0.x, e3y = v3.y - v0.y, e3z = v3.z - v0.z;

    float det = e1x * (e2y * e3z - e2z * e3y)
              - e1y * (e2x * e3z - e2z * e3x)
              + e1z * (e2x * e3y - e2y * e3x);
    area = fabsf(det) * (1.0f / 6.0f);

    float q01 = e1x * e1x + e1y * e1y + e1z * e1z;
    float q02 = e2x * e2x + e2y * e2y + e2z * e2z;
    float q03 = e3x * e3x + e3y * e3y + e3z * e3z;
    float ax, ay, az;
    ax = v1.x - v2.x; ay = v1.y - v2.y; az = v1.z - v2.z;
    float q12 = ax * ax + ay * ay + az * az;
    ax = v1.x - v3.x; ay = v1.y - v3.y; az = v1.z - v3.z;
    float q13 = ax * ax + ay * ay + az * az;
    ax = v2.x - v3.x; ay = v2.y - v3.y; az = v2.z - v3.z;
    float q23 = ax * ax + ay * ay + az * az;

    float mn = fminf(fminf(fminf(q01, q02), fminf(q03, q12)), fminf(q13, q23));
    float el = sqrtf(mn);
    alpha = 1.0f - expf(-d * el);
}

__device__ __forceinline__ V3 load_vert(const float* __restrict__ verts, int idx) {
    const float* p = verts + (size_t)idx * 3;
    V3 r; r.x = p[0]; r.y = p[1]; r.z = p[2];
    return r;
}

// L2-local atomic umax (no sc bits): RMW at the issuing XCD's TCC.
__device__ __forceinline__ void atomic_umax_l2(unsigned int* p, unsigned int v) {
    asm volatile("global_atomic_umax %0, %1, off" : : "v"(p), "v"(v) : "memory");
}

// ---------------- kernel 1: geometry only (no atomics) ----------------
__global__ __launch_bounds__(256) void tet_geom_kernel(
    const float* __restrict__ verts,
    const int*   __restrict__ indices,
    const float* __restrict__ density,
    float* __restrict__ out_area,
    float* __restrict__ out_alpha,
    int T)
{
    int tid = blockIdx.x * blockDim.x + threadIdx.x;
    int H = T >> 1;
    if (tid >= H) return;
    int i0 = tid, i1 = tid + H;

    vint4 idxA = __builtin_nontemporal_load((const vint4*)indices + i0);
    vint4 idxB = __builtin_nontemporal_load((const vint4*)indices + i1);
    float dA   = __builtin_nontemporal_load(density + i0);
    float dB   = __builtin_nontemporal_load(density + i1);

    V3 a0 = load_vert(verts, idxA.x);
    V3 a1 = load_vert(verts, idxA.y);
    V3 a2 = load_vert(verts, idxA.z);
    V3 a3 = load_vert(verts, idxA.w);
    V3 b0 = load_vert(verts, idxB.x);
    V3 b1 = load_vert(verts, idxB.y);
    V3 b2 = load_vert(verts, idxB.z);
    V3 b3 = load_vert(verts, idxB.w);

    float areaA, alphaA, areaB, alphaB;
    compute_tet(a0, a1, a2, a3, dA, areaA, alphaA);
    compute_tet(b0, b1, b2, b3, dB, areaB, alphaB);

    __builtin_nontemporal_store(areaA,  out_area + i0);
    __builtin_nontemporal_store(areaB,  out_area + i1);
    __builtin_nontemporal_store(alphaA, out_alpha + i0);
    __builtin_nontemporal_store(alphaB, out_alpha + i1);
}

// ---------------- kernel 2: XCD-sharded segment-max ----------------
// Every XCD scans all tets (via a per-XCD chunk queue) and applies atomics only
// to vertices in its private 1/8 slice of vd. Slice (512 KB) stays L2-resident;
// atomics are L2-local (no fabric messages). Slices disjoint -> vd written directly.
__global__ __launch_bounds__(256) void vd_shard_kernel(
    const int*   __restrict__ indices,
    const float* __restrict__ density,
    unsigned int* __restrict__ vd,
    unsigned int* __restrict__ counters,   // NUM_XCD queue counters (zeroed)
    int T, int V)
{
    __shared__ int s_chunk;

    unsigned int xcc;
    asm volatile("s_getreg_b32 %0, hwreg(HW_REG_XCC_ID)" : "=s"(xcc));
    xcc &= (NUM_XCD - 1);

    unsigned int per = (unsigned int)(V / NUM_XCD);
    unsigned int lo = xcc * per;
    unsigned int hi = (xcc == NUM_XCD - 1) ? (unsigned int)V : lo + per;

    const int CHUNK = 16384;
    int nchunks = (T + CHUNK - 1) / CHUNK;

    for (;;) {
        __syncthreads();
        if (threadIdx.x == 0)
            s_chunk = atomicAdd(counters + xcc, 1);   // device-scope queue pop
        __syncthreads();
        int c = s_chunk;
        if (c >= nchunks) break;

        int base = c * CHUNK;
        int end  = base + CHUNK; if (end > T) end = T;
        for (int i = base + (int)threadIdx.x; i < end; i += 256) {
            vint4 q = __builtin_nontemporal_load((const vint4*)indices + i);
            float d = __builtin_nontemporal_load(density + i);
            unsigned int db = __float_as_uint(d);   // d>=0: uint max == float max
            unsigned int x = (unsigned int)q.x, y = (unsigned int)q.y;
            unsigned int z = (unsigned int)q.z, w = (unsigned int)q.w;
            if (x >= lo && x < hi) atomic_umax_l2(vd + x, db);
            if (y >= lo && y < hi) atomic_umax_l2(vd + y, db);
            if (z >= lo && z < hi) atomic_umax_l2(vd + z, db);
            if (w >= lo && w < hi) atomic_umax_l2(vd + w, db);
        }
    }
    // Drain asm-issued atomics before wave exit.
    asm volatile("s_waitcnt vmcnt(0)" ::: "memory");
}

// ---------------- fallback path (round-3 proven, needs no ws) ----------------
__global__ __launch_bounds__(256) void zero_vd_kernel(float4* __restrict__ vd4, int n4) {
    int i = blockIdx.x * blockDim.x + threadIdx.x;
    if (i < n4) vd4[i] = make_float4(0.f, 0.f, 0.f, 0.f);
}

__global__ __launch_bounds__(256) void tet_kernel_fb(
    const float* __restrict__ verts,
    const int*   __restrict__ indices,
    const float* __restrict__ density,
    float* __restrict__ out_area,
    float* __restrict__ out_alpha,
    unsigned int* __restrict__ vd,
    int T)
{
    int tid = blockIdx.x * blockDim.x + threadIdx.x;
    int H = T >> 1;
    if (tid >= H) return;
    int i0 = tid, i1 = tid + H;

    vint4 idxA = __builtin_nontemporal_load((const vint4*)indices + i0);
    vint4 idxB = __builtin_nontemporal_load((const vint4*)indices + i1);
    float dA   = __builtin_nontemporal_load(density + i0);
    float dB   = __builtin_nontemporal_load(density + i1);

    V3 a0 = load_vert(verts, idxA.x);
    V3 a1 = load_vert(verts, idxA.y);
    V3 a2 = load_vert(verts, idxA.z);
    V3 a3 = load_vert(verts, idxA.w);
    V3 b0 = load_vert(verts, idxB.x);
    V3 b1 = load_vert(verts, idxB.y);
    V3 b2 = load_vert(verts, idxB.z);
    V3 b3 = load_vert(verts, idxB.w);

    float areaA, alphaA, areaB, alphaB;
    compute_tet(a0, a1, a2, a3, dA, areaA, alphaA);
    compute_tet(b0, b1, b2, b3, dB, areaB, alphaB);

    __builtin_nontemporal_store(areaA,  out_area + i0);
    __builtin_nontemporal_store(areaB,  out_area + i1);
    __builtin_nontemporal_store(alphaA, out_alpha + i0);
    __builtin_nontemporal_store(alphaB, out_alpha + i1);

    unsigned int dbA = __float_as_uint(dA);
    unsigned int dbB = __float_as_uint(dB);
    atomicMax(vd + idxA.x, dbA);
    atomicMax(vd + idxA.y, dbA);
    atomicMax(vd + idxA.z, dbA);
    atomicMax(vd + idxA.w, dbA);
    atomicMax(vd + idxB.x, dbB);
    atomicMax(vd + idxB.y, dbB);
    atomicMax(vd + idxB.z, dbB);
    atomicMax(vd + idxB.w, dbB);
}

extern "C" void kernel_launch(void* const* d_in, const int* in_sizes, int n_in,
                              void* d_out, int out_size, void* d_ws, size_t ws_size,
                              hipStream_t stream) {
    const float* verts   = (const float*)d_in[0];
    const int*   indices = (const int*)d_in[1];
    const float* density = (const float*)d_in[2];
    int T = in_sizes[2];        // 4,000,000 tets
    int V = in_sizes[0] / 3;    // 1,000,000 vertices

    float* out       = (float*)d_out;
    float* out_area  = out;
    float* out_alpha = out + (size_t)T;
    unsigned int* vd = (unsigned int*)(out + 2 * (size_t)T);

    const int block = 256;
    int H = T >> 1;
    int grid_g = (H + block - 1) / block;

    if (ws_size >= 4096) {
        unsigned int* counters = (unsigned int*)d_ws;

        // zero vd (max identity; harness poisons d_out) and the queue counters
        hipMemsetAsync(vd, 0, (size_t)V * sizeof(unsigned int), stream);
        hipMemsetAsync(counters, 0, 4096, stream);

        // scatter (XCD-sharded, L2-local atomics)
        vd_shard_kernel<<<2048, block, 0, stream>>>(indices, density, vd,
                                                    counters, T, V);

        // geometry (no atomics)
        tet_geom_kernel<<<grid_g, block, 0, stream>>>(verts, indices, density,
                                                      out_area, out_alpha, T);
    } else {
        int n4 = V / 4;
        int grid_z = (n4 + block - 1) / block;
        zero_vd_kernel<<<grid_z, block, 0, stream>>>((float4*)vd, n4);
        tet_kernel_fb<<<grid_g, block, 0, stream>>>(verts, indices, density,
                                                    out_area, out_alpha, vd, T);
    }
}